// Round 8
// baseline (52.562 us; speedup 1.0000x reference)
//
#include <hip/hip_runtime.h>
#include <cstddef>

#define B_ 32
#define N_ 128
#define D_ 128
#define IT 8
#define NEG_SLOPE 0.01f

typedef float v4f __attribute__((ext_vector_type(4)));

// One block per (b, 8 consecutive i). 256 threads: d4 = t&31, jg = t>>5.
// Hot loop: depth-1 software-pipelined ej prefetch; 8 dependency-free stores
// per iteration from registers; score partials via h=ei*w + 5-shfl butterfly.
// Tail: per-wave shfl softmax, 2 rows per wave.
__global__ void __launch_bounds__(256)
fused_value_attn_kernel(const float* __restrict__ e,
                        const float* __restrict__ w,
                        const float* __restrict__ bias,
                        float* __restrict__ alphas,
                        float* __restrict__ value) {
    const int blk = blockIdx.x;            // b * (N/IT) + itile
    const int b   = blk >> 4;              // N/IT = 16
    const int i0  = (blk & 15) << 3;       // IT = 8
    const int t   = threadIdx.x;
    const int d4  = t & 31;
    const int jg  = t >> 5;                // 0..7

    __shared__ float sc[IT][N_];

    const v4f* __restrict__ e4 = reinterpret_cast<const v4f*>(e);
    const v4f w4 = reinterpret_cast<const v4f*>(w)[d4];

    v4f ei4[IT], h4[IT];
#pragma unroll
    for (int q = 0; q < IT; ++q) {
        const int bi = (b << 7) | (i0 + q);
        ei4[q] = e4[(size_t)bi * 32 + d4];
        h4[q]  = ei4[q] * w4;              // score dot: sum(v*w) = sum(h*ej)
    }
    v4f* __restrict__ vout0 = reinterpret_cast<v4f*>(
        value + ((size_t)((b << 7) | i0)) * N_ * D_);

    // depth-1 prefetch: ejn holds iteration jj+1's row while jj stores
    v4f ejn = e4[((size_t)((b << 7) | jg)) * 32 + d4];
#pragma unroll 2
    for (int jj = 0; jj < 16; ++jj) {
        const int j = (jj << 3) + jg;      // 0..127
        const v4f ejc = ejn;
        if (jj < 15)
            ejn = e4[((size_t)((b << 7) | (j + 8))) * 32 + d4];
#pragma unroll
        for (int q = 0; q < IT; ++q) {
            vout0[(size_t)q * (N_ * 32) + (j << 5) + d4] = ei4[q] * ejc;
            const v4f pw = h4[q] * ejc;
            float p = pw.x + pw.y + pw.z + pw.w;
            p += __shfl_xor(p, 1);
            p += __shfl_xor(p, 2);
            p += __shfl_xor(p, 4);
            p += __shfl_xor(p, 8);
            p += __shfl_xor(p, 16);
            if (d4 == 0) sc[q][j] = p;
        }
    }
    __syncthreads();

    // Tail: wave wv handles rows q = 2*wv, 2*wv+1. Lane l covers j=l, l+64.
    const int wv = t >> 6;                 // 0..3
    const int l  = t & 63;
    const float bias0 = bias[0];
#pragma unroll
    for (int r = 0; r < 2; ++r) {
        const int q = (wv << 1) + r;
        float s0 = sc[q][l]      + bias0;
        float s1 = sc[q][l + 64] + bias0;
        s0 = (s0 >= 0.f) ? s0 : NEG_SLOPE * s0;
        s1 = (s1 >= 0.f) ? s1 : NEG_SLOPE * s1;
        float m = fmaxf(s0, s1);
#pragma unroll
        for (int off = 32; off > 0; off >>= 1) m = fmaxf(m, __shfl_xor(m, off));
        const float e0 = expf(s0 - m), e1 = expf(s1 - m);
        float sum = e0 + e1;
#pragma unroll
        for (int off = 32; off > 0; off >>= 1) sum += __shfl_xor(sum, off);
        const float inv = 1.f / sum;
        float* arow = alphas + ((size_t)((b << 7) | (i0 + q))) * N_;
        arow[l]      = e0 * inv;
        arow[l + 64] = e1 * inv;
    }
}

extern "C" void kernel_launch(void* const* d_in, const int* in_sizes, int n_in,
                              void* d_out, int out_size, void* d_ws, size_t ws_size,
                              hipStream_t stream) {
    const float* e    = (const float*)d_in[0];   // [B, N, D]
    const float* w    = (const float*)d_in[1];   // [D]
    const float* bias = (const float*)d_in[2];   // [1]

    float* out    = (float*)d_out;
    float* alphas = out;                              // B*N*N
    float* value  = out + (size_t)B_ * N_ * N_;       // B*N*N*D

    fused_value_attn_kernel<<<(B_ * N_) / IT, 256, 0, stream>>>(e, w, bias, alphas, value);
}

// Round 9
// 49.651 us; speedup vs baseline: 1.0586x; 1.0586x over previous
//
#include <hip/hip_runtime.h>
#include <cstddef>

#define B_ 32
#define N_ 128
#define D_ 128
#define NEG_SLOPE 0.01f

typedef float v4f __attribute__((ext_vector_type(4)));

// Best-proven structure (R2, 49.7us): one block per (b,i), 256 threads,
// t -> (d4 = t&31, jg = t>>5). 16 iterations (unroll 4) over j: load ej,
// store value row chunk, score partial via shfl butterfly. Block softmax tail.
// Ablations that did NOT beat this: nontemporal stores (58-64us), phase-split
// w/ full unroll (59-64us), i-tiling IT=4/8 (49.9/52.6us), depth-1 prefetch.
// Output is 270 MB mandatory stream writes; 49.7us = 5.4 TB/s effective
// (~78% of the 7.0 TB/s pure-fill rate incl. dispatch overhead) -> roofline.
__global__ void __launch_bounds__(256)
fused_value_attn_kernel(const float* __restrict__ e,
                        const float* __restrict__ w,
                        const float* __restrict__ bias,
                        float* __restrict__ alphas,
                        float* __restrict__ value) {
    const int bi = blockIdx.x;          // b*N + i
    const int b  = bi >> 7;
    const int t  = threadIdx.x;
    const int d4 = t & 31;              // which v4f of the D=128 row
    const int jg = t >> 5;              // 0..7

    __shared__ float sc[N_];
    __shared__ float red[N_];

    const v4f* __restrict__ e4 = reinterpret_cast<const v4f*>(e);
    const v4f w4  = reinterpret_cast<const v4f*>(w)[d4];
    const v4f ei4 = e4[(size_t)bi * 32 + d4];
    const float bias0 = bias[0];

    v4f* __restrict__ vout = reinterpret_cast<v4f*>(
        value + (size_t)bi * N_ * D_);

#pragma unroll 4
    for (int jj = 0; jj < 16; ++jj) {
        const int j = (jj << 3) + jg;   // 0..127
        const v4f ej4 = e4[((size_t)((b << 7) | j)) * 32 + d4];
        const v4f v4 = ei4 * ej4;

        vout[(j << 5) + d4] = v4;

        // partial score: sum_d v[d]*w[d] over this thread's 4 d's
        const v4f pw = v4 * w4;
        float p = pw.x + pw.y + pw.z + pw.w;
        // butterfly over the 32 lanes sharing this j
        p += __shfl_xor(p, 1);
        p += __shfl_xor(p, 2);
        p += __shfl_xor(p, 4);
        p += __shfl_xor(p, 8);
        p += __shfl_xor(p, 16);
        if (d4 == 0) sc[j] = p;
    }
    __syncthreads();

    // Softmax over j (threads 0..127 own one j each; all threads hit barriers)
    float s = 0.f, ex = 0.f;
    if (t < N_) {
        s = sc[t] + bias0;
        s = (s >= 0.f) ? s : NEG_SLOPE * s;
        red[t] = s;
    }
    __syncthreads();
#pragma unroll
    for (int off = 64; off > 0; off >>= 1) {
        if (t < off) red[t] = fmaxf(red[t], red[t + off]);
        __syncthreads();
    }
    const float m = red[0];
    __syncthreads();
    if (t < N_) { ex = expf(s - m); red[t] = ex; }
    __syncthreads();
#pragma unroll
    for (int off = 64; off > 0; off >>= 1) {
        if (t < off) red[t] += red[t + off];
        __syncthreads();
    }
    if (t < N_) alphas[(size_t)bi * N_ + t] = ex / red[0];
}

extern "C" void kernel_launch(void* const* d_in, const int* in_sizes, int n_in,
                              void* d_out, int out_size, void* d_ws, size_t ws_size,
                              hipStream_t stream) {
    const float* e    = (const float*)d_in[0];   // [B, N, D]
    const float* w    = (const float*)d_in[1];   // [D]
    const float* bias = (const float*)d_in[2];   // [1]

    float* out    = (float*)d_out;
    float* alphas = out;                              // B*N*N
    float* value  = out + (size_t)B_ * N_ * N_;       // B*N*N*D

    fused_value_attn_kernel<<<B_ * N_, 256, 0, stream>>>(e, w, bias, alphas, value);
}